// Round 10
// baseline (2162.122 us; speedup 1.0000x reference)
//
#include <hip/hip_runtime.h>
#include <hip/hip_fp16.h>

#define NN 100000
#define NE 1600000
#define NG 256
#define NSL 196                              // src slices of 512 nodes (64KB fp16)
#define NBKTD ((NN + 127) / 128)             // 782 dst buckets of 128 nodes
#define CAPD 2688                            // per-bucket cap (mean 2046, +14 sigma)
#define TILE_A 4096
#define NBLK_A ((NE + TILE_A - 1) / TILE_A)  // 391

typedef _Float16 f16x8 __attribute__((ext_vector_type(8)));
typedef float f32x4 __attribute__((ext_vector_type(4)));

struct W12 { const float* w[12]; };

__device__ __forceinline__ uint2 f4_to_h16(float4 o) {
    __half2 lo = __floats2half2_rn(o.x, o.y);
    __half2 hi = __floats2half2_rn(o.z, o.w);
    uint2 u;
    u.x = *(unsigned int*)&lo;
    u.y = *(unsigned int*)&hi;
    return u;
}

// ---------------- binA: wprep + cvt prologue, then dst-bucket binning ----------------
// edge pack: v = (src<<7) | (dst & 127);  bucket = dst>>7.  gcur = per-bucket counts.
__global__ __launch_bounds__(256) void binA_kernel(const int* __restrict__ src,
                                                   const int* __restrict__ dst,
                                                   int* __restrict__ gcur,
                                                   unsigned int* __restrict__ binned,
                                                   const float* __restrict__ x,
                                                   __half* __restrict__ hX16,
                                                   W12 wm, __half* __restrict__ wt)
{
    __shared__ int hist[NBKTD];
    __shared__ int cnt2[NBKTD];
    __shared__ int lexcl[NBKTD];
    __shared__ int base[NBKTD];
    __shared__ int s[256];
    __shared__ unsigned int buf[TILE_A];
    __shared__ unsigned short bkt16[TILE_A];

    const int t = threadIdx.x;
    const int gt = blockIdx.x * 256 + t;
    const int gs = gridDim.x * 256;

    // prologue 1: weight prep, 12 mats fp32 [k][n] -> fp16 [n][k]
    for (int i = gt; i < 12 * 4096; i += gs) {
        const int m = i >> 12, e = i & 4095;
        const int n = e >> 6, k = e & 63;
        wt[m * 4096 + n * 64 + k] = __float2half(wm.w[m][k * 64 + n]);
    }
    // prologue 2: cvt x fp32 -> fp16
    for (int i = gt; i < NN * 64 / 4; i += gs) {
        float4 v = ((const float4*)x)[i];
        ((uint2*)hX16)[i] = f4_to_h16(v);
    }

    for (int tile = blockIdx.x; tile < NBLK_A; tile += gridDim.x) {
        const int e0 = tile * TILE_A;
        const int nedge = min(TILE_A, NE - e0);
        __syncthreads();
        for (int i = t; i < NBKTD; i += 256) { hist[i] = 0; cnt2[i] = 0; }
        __syncthreads();

        for (int j = t; j < nedge; j += 256)
            atomicAdd(&hist[dst[e0 + j] >> 7], 1);
        __syncthreads();

        // exclusive scan over 782 bucket counts (4-per-thread chunks + 256-scan)
        const int l0 = t * 4;
        int csum = 0;
        #pragma unroll
        for (int j = 0; j < 4; ++j)
            if (l0 + j < NBKTD) csum += hist[l0 + j];
        s[t] = csum;
        __syncthreads();
        for (int off = 1; off < 256; off <<= 1) {
            int u = (t >= off) ? s[t - off] : 0;
            __syncthreads();
            s[t] += u;
            __syncthreads();
        }
        int run = s[t] - csum;
        #pragma unroll
        for (int j = 0; j < 4; ++j) {
            const int b = l0 + j;
            if (b < NBKTD) {
                lexcl[b] = run;
                const int h = hist[b];
                run += h;
                if (h > 0) base[b] = b * CAPD + atomicAdd(&gcur[b], h);
            }
        }
        __syncthreads();

        for (int j = t; j < nedge; j += 256) {
            const int d = dst[e0 + j];
            const int sv = src[e0 + j];
            const int b = d >> 7;
            const int r = atomicAdd(&cnt2[b], 1);
            const int idx = lexcl[b] + r;
            buf[idx] = ((unsigned int)sv << 7) | (unsigned int)(d & 127);
            bkt16[idx] = (unsigned short)b;
        }
        __syncthreads();

        for (int j = t; j < nedge; j += 256) {
            const int b = bkt16[j];
            binned[base[b] + (j - lexcl[b])] = buf[j];
        }
    }
}

// ---------------- binB: per-bucket counting sort by src-slice (in place) ----------------
__global__ __launch_bounds__(256) void binB_kernel(unsigned int* __restrict__ binned,
                                                   const int* __restrict__ gcur)
{
    __shared__ unsigned int buf[CAPD];
    __shared__ int cnt[NSL];
    __shared__ int excl[NSL];
    __shared__ int cnt2[NSL];
    __shared__ int psum[256];

    const int b = blockIdx.x;
    const int t = threadIdx.x;
    const int sz = min(gcur[b], CAPD);
    unsigned int* bp = binned + b * CAPD;

    if (t < NSL) { cnt[t] = 0; cnt2[t] = 0; }
    __syncthreads();

    for (int j = t; j < sz; j += 256) {
        const unsigned int v = bp[j];
        buf[j] = v;
        atomicAdd(&cnt[v >> 16], 1);   // slice = src>>9 = v>>16
    }
    __syncthreads();

    psum[t] = (t < NSL) ? cnt[t] : 0;
    __syncthreads();
    for (int off = 1; off < 256; off <<= 1) {
        int u = (t >= off) ? psum[t - off] : 0;
        __syncthreads();
        psum[t] += u;
        __syncthreads();
    }
    if (t < NSL) excl[t] = psum[t] - cnt[t];
    __syncthreads();

    for (int j = t; j < sz; j += 256) {
        const unsigned int v = buf[j];
        const int k = v >> 16;
        const int r = atomicAdd(&cnt2[k], 1);
        bp[excl[k] + r] = v;
    }
}

// ---------------- fused GNN layer: bucket-owner LDS-accum + MFMA ----------------
// out = relu( h@Wa+ba + agg(h)@Wc+bc + (h@Wb+bb)*(h@Wd+bd) )
// Block owns one 128-node dst bucket. Phase A: stream slice-sorted edges,
// accumulate rows into skewed f-major fp32 LDS acc via ds atomics (src-slice
// locality -> L2-resident gather). Phase B: 4x 32-node MFMA passes.
__global__ __launch_bounds__(256) void layer_kernel(
    const __half* __restrict__ h_in, __half* __restrict__ h_out,
    const unsigned int* __restrict__ binned, const int* __restrict__ gcur,
    const __half* __restrict__ wt,
    const float* __restrict__ ba, const float* __restrict__ bc,
    const float* __restrict__ bb, const float* __restrict__ bd)
{
    __shared__ float acc[64 * 128];          // f-major, skewed: acc[f*128 + ((d+f)&127)]
    __shared__ unsigned int sEdge[CAPD];
    __shared__ _Float16 sX1[32][72];
    __shared__ _Float16 sX2[32][72];

    const int tid = threadIdx.x;
    const int b = blockIdx.x;
    const int node0 = b << 7;
    const int sz = min(gcur[b], CAPD);

    // mfma indexing
    const int w = tid >> 6, l = tid & 63, lr = l & 15, kh = l >> 4;
    const int col = w * 16 + lr;
    const _Float16* wtf = (const _Float16*)wt;
    const f16x8 wrA0 = *(const f16x8*)&wtf[0 * 4096 + col * 64 + kh * 8];
    const f16x8 wrA1 = *(const f16x8*)&wtf[0 * 4096 + col * 64 + 32 + kh * 8];
    const f16x8 wrC0 = *(const f16x8*)&wtf[1 * 4096 + col * 64 + kh * 8];
    const f16x8 wrC1 = *(const f16x8*)&wtf[1 * 4096 + col * 64 + 32 + kh * 8];
    const f16x8 wrB0 = *(const f16x8*)&wtf[2 * 4096 + col * 64 + kh * 8];
    const f16x8 wrB1 = *(const f16x8*)&wtf[2 * 4096 + col * 64 + 32 + kh * 8];
    const f16x8 wrD0 = *(const f16x8*)&wtf[3 * 4096 + col * 64 + kh * 8];
    const f16x8 wrD1 = *(const f16x8*)&wtf[3 * 4096 + col * 64 + 32 + kh * 8];
    const float bA = ba[col], bC = bc[col], bB = bb[col], bD = bd[col];

    // init acc + stage edges
    for (int i = tid; i < 64 * 128; i += 256) acc[i] = 0.f;
    for (int j = tid; j < sz; j += 256) sEdge[j] = binned[b * CAPD + j];
    __syncthreads();

    // ---- phase A: edge aggregation (2 edges per lane-iter, loads first) ----
    const int ep = tid >> 3;       // 0..31 edge slot
    const int fg8 = tid & 7;       // 16B feature chunk
    for (int i0 = 0; i0 < sz; i0 += 64) {
        const int e0 = i0 + ep;
        const int e1 = i0 + 32 + ep;
        const bool q0 = e0 < sz, q1 = e1 < sz;
        const unsigned int v0 = q0 ? sEdge[e0] : 0u;
        const unsigned int v1 = q1 ? sEdge[e1] : 0u;
        uint4 u0, u1;
        if (q0) u0 = *(const uint4*)(h_in + (v0 >> 7) * 64 + fg8 * 8);
        if (q1) u1 = *(const uint4*)(h_in + (v1 >> 7) * 64 + fg8 * 8);
        if (q0) {
            const int d = v0 & 127;
            const __half2* hp = (const __half2*)&u0;
            #pragma unroll
            for (int q = 0; q < 4; ++q) {
                float2 f2 = __half22float2(hp[q]);
                const int f0 = fg8 * 8 + 2 * q;
                atomicAdd(&acc[f0 * 128 + ((d + f0) & 127)], f2.x);
                atomicAdd(&acc[(f0 + 1) * 128 + ((d + f0 + 1) & 127)], f2.y);
            }
        }
        if (q1) {
            const int d = v1 & 127;
            const __half2* hp = (const __half2*)&u1;
            #pragma unroll
            for (int q = 0; q < 4; ++q) {
                float2 f2 = __half22float2(hp[q]);
                const int f0 = fg8 * 8 + 2 * q;
                atomicAdd(&acc[f0 * 128 + ((d + f0) & 127)], f2.x);
                atomicAdd(&acc[(f0 + 1) * 128 + ((d + f0 + 1) & 127)], f2.y);
            }
        }
    }
    __syncthreads();

    // ---- phase B: 4 passes of 32 nodes ----
    const int slot = tid >> 3;     // 0..31
    for (int p = 0; p < 4; ++p) {
        const int nl = p * 32 + slot;         // node-local 0..127
        const int node = node0 + nl;

        uint4 hreg = make_uint4(0u, 0u, 0u, 0u);
        if (node < NN) hreg = *(const uint4*)(h_in + node * 64 + fg8 * 8);

        union { _Float16 h[8]; uint4 u; } cv;
        #pragma unroll
        for (int j = 0; j < 8; ++j) {
            const int f = fg8 * 8 + j;
            cv.h[j] = (_Float16)acc[f * 128 + ((nl + f) & 127)];
        }

        *(uint4*)&sX1[slot][fg8 * 8] = hreg;
        *(uint4*)&sX2[slot][fg8 * 8] = cv.u;
        __syncthreads();

        f32x4 accA1 = {0.f,0.f,0.f,0.f}, accC1 = {0.f,0.f,0.f,0.f};
        f32x4 accB1 = {0.f,0.f,0.f,0.f}, accD1 = {0.f,0.f,0.f,0.f};
        f32x4 accA2 = {0.f,0.f,0.f,0.f}, accC2 = {0.f,0.f,0.f,0.f};
        f32x4 accB2 = {0.f,0.f,0.f,0.f}, accD2 = {0.f,0.f,0.f,0.f};
        #pragma unroll
        for (int kk = 0; kk < 2; ++kk) {
            const int ko = kk * 32 + kh * 8;
            const f16x8 wa = kk ? wrA1 : wrA0;
            const f16x8 wc = kk ? wrC1 : wrC0;
            const f16x8 wb = kk ? wrB1 : wrB0;
            const f16x8 wd = kk ? wrD1 : wrD0;
            const f16x8 a1r0 = *(const f16x8*)&sX1[lr][ko];
            const f16x8 a2r0 = *(const f16x8*)&sX2[lr][ko];
            const f16x8 a1r1 = *(const f16x8*)&sX1[16 + lr][ko];
            const f16x8 a2r1 = *(const f16x8*)&sX2[16 + lr][ko];
            accA1 = __builtin_amdgcn_mfma_f32_16x16x32_f16(a1r0, wa, accA1, 0, 0, 0);
            accC1 = __builtin_amdgcn_mfma_f32_16x16x32_f16(a2r0, wc, accC1, 0, 0, 0);
            accB1 = __builtin_amdgcn_mfma_f32_16x16x32_f16(a1r0, wb, accB1, 0, 0, 0);
            accD1 = __builtin_amdgcn_mfma_f32_16x16x32_f16(a1r0, wd, accD1, 0, 0, 0);
            accA2 = __builtin_amdgcn_mfma_f32_16x16x32_f16(a1r1, wa, accA2, 0, 0, 0);
            accC2 = __builtin_amdgcn_mfma_f32_16x16x32_f16(a2r1, wc, accC2, 0, 0, 0);
            accB2 = __builtin_amdgcn_mfma_f32_16x16x32_f16(a1r1, wb, accB2, 0, 0, 0);
            accD2 = __builtin_amdgcn_mfma_f32_16x16x32_f16(a1r1, wd, accD2, 0, 0, 0);
        }

        const int nb = node0 + p * 32;
        #pragma unroll
        for (int r = 0; r < 4; ++r) {
            int nd = nb + kh * 4 + r;
            if (nd < NN) {
                float o = fmaxf((accA1[r] + bA) + (accC1[r] + bC) +
                                (accB1[r] + bB) * (accD1[r] + bD), 0.f);
                h_out[nd * 64 + col] = __float2half(o);
            }
            nd += 16;
            if (nd < NN) {
                float o = fmaxf((accA2[r] + bA) + (accC2[r] + bC) +
                                (accB2[r] + bB) * (accD2[r] + bD), 0.f);
                h_out[nd * 64 + col] = __float2half(o);
            }
        }
        __syncthreads();   // protect sX before next pass overwrites
    }
}

// ---------------- pool + MLP ----------------
__global__ __launch_bounds__(256) void pool_mlp_kernel(
    const __half* __restrict__ h, const int* __restrict__ batch,
    const float* __restrict__ w1, const float* __restrict__ b1,
    const float* __restrict__ w2, const float* __restrict__ b2,
    float* __restrict__ out)
{
    const int g = blockIdx.x;
    const int t = threadIdx.x;
    int lo = 0, hi = NN;
    while (lo < hi) { int m = (lo + hi) >> 1; if (batch[m] < g) lo = m + 1; else hi = m; }
    const int start = lo;
    hi = NN;
    while (lo < hi) { int m = (lo + hi) >> 1; if (batch[m] < g + 1) lo = m + 1; else hi = m; }
    const int end = lo;

    const int f = t & 63, wsub = t >> 6;
    float sum = 0.f;
    for (int n = start + wsub; n < end; n += 4) sum += __half2float(h[n * 64 + f]);
    __shared__ float red[4][64];
    red[wsub][f] = sum;
    __syncthreads();
    __shared__ float pooled[64];
    if (t < 64) {
        float tot = red[0][t] + red[1][t] + red[2][t] + red[3][t];
        pooled[t] = tot / fmaxf((float)(end - start), 1.f);
    }
    __syncthreads();
    __shared__ float y10[10];
    if (t < 10) {
        float acc = b1[t];
        for (int k = 0; k < 64; ++k) acc = fmaf(pooled[k], w1[k * 10 + t], acc);
        y10[t] = acc;
    }
    __syncthreads();
    if (t == 0) {
        float acc = b2[0];
        for (int j = 0; j < 10; ++j) acc = fmaf(y10[j], w2[j], acc);
        out[g] = acc;
    }
}

extern "C" void kernel_launch(void* const* d_in, const int* in_sizes, int n_in,
                              void* d_out, int out_size, void* d_ws, size_t ws_size,
                              hipStream_t stream) {
    const float* x   = (const float*)d_in[0];
    const int* ei    = (const int*)d_in[1];
    const int* batch = (const int*)d_in[2];
    const int* src   = ei;
    const int* dstv  = ei + NE;

    // workspace layout (bytes), total ~35MB:
    //   hX16: [0, 12.8M)   hA16: [12.8M, 25.6M)
    //   binned: [25.6M, +8.41M)   gcur: [34.5M, +3128)   wt: [34.6M, +98304)
    char* ws     = (char*)d_ws;
    __half* hX16 = (__half*)(ws);
    __half* hA16 = (__half*)(ws + 12800000);
    unsigned int* binned = (unsigned int*)(ws + 25600000);
    int* gcur    = (int*)(ws + 34500000);
    __half* wt   = (__half*)(ws + 34600000);

    auto f = [&](int i) { return (const float*)d_in[i]; };
    W12 wm;
    const int wmidx[12] = {5, 3, 7, 9, 13, 11, 15, 17, 21, 19, 23, 25};
    for (int i = 0; i < 12; ++i) wm.w[i] = f(wmidx[i]);

    hipMemsetAsync(gcur, 0, NBKTD * sizeof(int), stream);
    binA_kernel<<<512, 256, 0, stream>>>(src, dstv, gcur, binned, x, hX16, wm, wt);
    binB_kernel<<<NBKTD, 256, 0, stream>>>(binned, gcur);

    layer_kernel<<<NBKTD, 256, 0, stream>>>(hX16, hA16, binned, gcur,
        wt,         f(6), f(4), f(8), f(10));
    layer_kernel<<<NBKTD, 256, 0, stream>>>(hA16, hX16, binned, gcur,
        wt + 16384, f(14), f(12), f(16), f(18));
    layer_kernel<<<NBKTD, 256, 0, stream>>>(hX16, hA16, binned, gcur,
        wt + 32768, f(22), f(20), f(24), f(26));

    pool_mlp_kernel<<<NG, 256, 0, stream>>>(hA16, batch,
        f(27), f(28), f(29), f(30), (float*)d_out);
}

// Round 11
// 210.953 us; speedup vs baseline: 10.2493x; 10.2493x over previous
//
#include <hip/hip_runtime.h>
#include <hip/hip_fp16.h>

#define NN 100000
#define NE 1600000
#define NG 256
#define NPB 32
#define LAYER_GRID 3136                      // one 32-node pass per block (3125 passes)
#define SIDX 1280

#define BSH 9
#define NBKT ((NN + 511) / 512)              // 196
#define CAP 9216
#define TILE_A 4096
#define NBLK_A ((NE + TILE_A - 1) / TILE_A)  // 391

typedef _Float16 f16x8 __attribute__((ext_vector_type(8)));
typedef float f32x4 __attribute__((ext_vector_type(4)));

struct W12 { const float* w[12]; };

__device__ __forceinline__ uint2 f4_to_h16(float4 o) {
    __half2 lo = __floats2half2_rn(o.x, o.y);
    __half2 hi = __floats2half2_rn(o.z, o.w);
    uint2 u;
    u.x = *(unsigned int*)&lo;
    u.y = *(unsigned int*)&hi;
    return u;
}

__device__ __forceinline__ void accu8(float* a8, uint4 u) {
    const __half2* hp = (const __half2*)&u;
    #pragma unroll
    for (int q = 0; q < 4; ++q) {
        float2 f = __half22float2(hp[q]);
        a8[2 * q] += f.x; a8[2 * q + 1] += f.y;
    }
}

// ---------------- binA: wprep + cvt prologue, then edge binning ----------------
// gcur holds per-bucket COUNTS (memset to 0 before launch).
__global__ __launch_bounds__(256) void binA_kernel(const int* __restrict__ src,
                                                   const int* __restrict__ dst,
                                                   int* __restrict__ gcur,
                                                   unsigned int* __restrict__ binned,
                                                   const float* __restrict__ x,
                                                   __half* __restrict__ hX16,
                                                   W12 wm, __half* __restrict__ wt)
{
    __shared__ int hist[NBKT];
    __shared__ int cnt2[NBKT];
    __shared__ int lexcl[NBKT];
    __shared__ int base[NBKT];
    __shared__ int s[256];
    __shared__ unsigned int buf[TILE_A];
    __shared__ unsigned char bkt8[TILE_A];

    const int t = threadIdx.x;
    const int gt = blockIdx.x * 256 + t;
    const int gs = gridDim.x * 256;

    // prologue 1: weight prep, 12 mats fp32 [k][n] -> fp16 [n][k]
    for (int i = gt; i < 12 * 4096; i += gs) {
        const int m = i >> 12, e = i & 4095;
        const int n = e >> 6, k = e & 63;
        wt[m * 4096 + n * 64 + k] = __float2half(wm.w[m][k * 64 + n]);
    }
    // prologue 2: cvt x fp32 -> fp16
    for (int i = gt; i < NN * 64 / 4; i += gs) {
        float4 v = ((const float4*)x)[i];
        ((uint2*)hX16)[i] = f4_to_h16(v);
    }

    // edge binning with LDS reorder (contiguous per-bucket runs to global)
    for (int tile = blockIdx.x; tile < NBLK_A; tile += gridDim.x) {
        const int e0 = tile * TILE_A;
        const int nedge = min(TILE_A, NE - e0);
        __syncthreads();
        if (t < NBKT) { hist[t] = 0; cnt2[t] = 0; }
        __syncthreads();

        for (int j = t; j < nedge; j += 256)
            atomicAdd(&hist[dst[e0 + j] >> BSH], 1);
        __syncthreads();

        s[t] = (t < NBKT) ? hist[t] : 0;
        __syncthreads();
        for (int off = 1; off < 256; off <<= 1) {
            int u = (t >= off) ? s[t - off] : 0;
            __syncthreads();
            s[t] += u;
            __syncthreads();
        }
        if (t < NBKT) {
            lexcl[t] = s[t] - hist[t];
            if (hist[t] > 0) base[t] = t * CAP + atomicAdd(&gcur[t], hist[t]);
        }
        __syncthreads();

        for (int j = t; j < nedge; j += 256) {
            const int d = dst[e0 + j];
            const int sv = src[e0 + j];
            const int b = d >> BSH;
            const int r = atomicAdd(&cnt2[b], 1);
            const int idx = lexcl[b] + r;
            buf[idx] = ((unsigned int)sv << BSH) | (unsigned int)(d & 511);
            bkt8[idx] = (unsigned char)b;
        }
        __syncthreads();

        for (int j = t; j < nedge; j += 256) {
            const int b = bkt8[j];
            binned[base[b] + (j - lexcl[b])] = buf[j];
        }
    }
}

// ---------------- binB: local bucket-base scan + per-bucket counting sort ----------------
__global__ __launch_bounds__(512) void binB_kernel(const unsigned int* __restrict__ binned,
                                                   const int* __restrict__ gcur,
                                                   int* __restrict__ csr,
                                                   int* __restrict__ rs)
{
    __shared__ int cnt[512];
    __shared__ int excl[512];
    __shared__ int cnt2[512];
    __shared__ int psum[256];
    __shared__ unsigned int buf[CAP];
    __shared__ int gbs;

    const int b = blockIdx.x;
    const int t = threadIdx.x;

    // local exclusive scan of bucket sizes -> this block's global base (threads <256)
    int szt = 0;
    if (t < 256) {
        szt = (t < NBKT) ? min(gcur[t], CAP) : 0;
        psum[t] = szt;
    }
    __syncthreads();
    for (int off = 1; off < 256; off <<= 1) {
        int u = 0;
        if (t < 256 && t >= off) u = psum[t - off];
        __syncthreads();
        if (t < 256) psum[t] += u;
        __syncthreads();
    }
    if (t == b) gbs = psum[t] - szt;   // b < NBKT=196 < 256
    __syncthreads();
    const int sz = min(gcur[b], CAP);
    const int gb = gbs;
    const unsigned int* bp = binned + b * CAP;

    cnt[t] = 0;
    cnt2[t] = 0;
    __syncthreads();

    for (int j = t; j < sz; j += 512) {
        const unsigned int v = bp[j];
        buf[j] = v;
        atomicAdd(&cnt[v & 511], 1);
    }
    __syncthreads();

    int c0 = 0, c1 = 0;
    if (t < 256) {
        c0 = cnt[2 * t]; c1 = cnt[2 * t + 1];
        psum[t] = c0 + c1;
    }
    __syncthreads();
    for (int off = 1; off < 256; off <<= 1) {
        int u = 0;
        if (t < 256 && t >= off) u = psum[t - off];
        __syncthreads();
        if (t < 256) psum[t] += u;
        __syncthreads();
    }
    if (t < 256) {
        const int pe = psum[t] - (c0 + c1);
        excl[2 * t] = pe;
        excl[2 * t + 1] = pe + c0;
    }
    __syncthreads();

    const int node0 = b << BSH;
    {
        const int node = node0 + t;
        if (t < 512 && node < NN) rs[node] = gb + excl[t];
    }
    for (int j = t; j < sz; j += 512) {
        const unsigned int v = buf[j];
        const int l = v & 511;
        const int r = atomicAdd(&cnt2[l], 1);
        csr[gb + excl[l] + r] = (int)(v >> BSH);
    }
    if (b == 0 && t == 0) rs[NN] = NE;
}

// ---------------- fused GNN layer: MFMA dense + gathered agg ----------------
__global__ __launch_bounds__(256) void layer_kernel(
    const __half* __restrict__ h_in, __half* __restrict__ h_out,
    const int* __restrict__ csr, const int* __restrict__ rs,
    const __half* __restrict__ wt,
    const float* __restrict__ ba, const float* __restrict__ bc,
    const float* __restrict__ bb, const float* __restrict__ bd)
{
    __shared__ _Float16 sX1[NPB][72];
    __shared__ _Float16 sX2[NPB][72];
    __shared__ int sIdx[SIDX];

    const int tid = threadIdx.x;
    const int slot = tid >> 3, fg8 = tid & 7;
    const int w = tid >> 6, l = tid & 63, lr = l & 15, kh = l >> 4;
    const int col = w * 16 + lr;

    const _Float16* wtf = (const _Float16*)wt;
    const f16x8 wrA0 = *(const f16x8*)&wtf[0 * 4096 + col * 64 + kh * 8];
    const f16x8 wrA1 = *(const f16x8*)&wtf[0 * 4096 + col * 64 + 32 + kh * 8];
    const f16x8 wrC0 = *(const f16x8*)&wtf[1 * 4096 + col * 64 + kh * 8];
    const f16x8 wrC1 = *(const f16x8*)&wtf[1 * 4096 + col * 64 + 32 + kh * 8];
    const f16x8 wrB0 = *(const f16x8*)&wtf[2 * 4096 + col * 64 + kh * 8];
    const f16x8 wrB1 = *(const f16x8*)&wtf[2 * 4096 + col * 64 + 32 + kh * 8];
    const f16x8 wrD0 = *(const f16x8*)&wtf[3 * 4096 + col * 64 + kh * 8];
    const f16x8 wrD1 = *(const f16x8*)&wtf[3 * 4096 + col * 64 + 32 + kh * 8];
    const float bA = ba[col], bC = bc[col], bB = bb[col], bD = bd[col];

    const int npass = (NN + NPB - 1) / NPB;
    for (int g = blockIdx.x; g < npass; g += gridDim.x) {
        const int node0 = g * NPB;
        const int e0 = rs[node0];
        const int eN = rs[min(node0 + NPB, NN)];
        const int staged = min(eN - e0, SIDX);

        __syncthreads();
        for (int j = tid; j < staged; j += 256) sIdx[j] = csr[e0 + j];
        __syncthreads();

        const int node = node0 + slot;
        uint4 hreg = make_uint4(0u, 0u, 0u, 0u);
        float a8[8] = {0.f, 0.f, 0.f, 0.f, 0.f, 0.f, 0.f, 0.f};
        if (node < NN) {
            hreg = *(const uint4*)(h_in + node * 64 + fg8 * 8);
            const int rsn = rs[node];
            const int ne = rs[node + 1] - rsn;
            const int le = rsn - e0;
            for (int q = 0; q < ne; q += 8) {
                const int rem = ne - q;
                const int jb = le + q;
                auto gi = [&](int i) {
                    const int jr = jb + i;
                    return (jr < staged) ? sIdx[jr] : csr[e0 + jr];
                };
                const int s0 = gi(0);
                const int s1 = rem > 1 ? gi(1) : s0;
                const int s2 = rem > 2 ? gi(2) : s0;
                const int s3 = rem > 3 ? gi(3) : s0;
                const int s4 = rem > 4 ? gi(4) : s0;
                const int s5 = rem > 5 ? gi(5) : s0;
                const int s6 = rem > 6 ? gi(6) : s0;
                const int s7 = rem > 7 ? gi(7) : s0;
                const uint4 u0 = *(const uint4*)(h_in + s0 * 64 + fg8 * 8);
                const uint4 u1 = *(const uint4*)(h_in + s1 * 64 + fg8 * 8);
                const uint4 u2 = *(const uint4*)(h_in + s2 * 64 + fg8 * 8);
                const uint4 u3 = *(const uint4*)(h_in + s3 * 64 + fg8 * 8);
                const uint4 u4 = *(const uint4*)(h_in + s4 * 64 + fg8 * 8);
                const uint4 u5 = *(const uint4*)(h_in + s5 * 64 + fg8 * 8);
                const uint4 u6 = *(const uint4*)(h_in + s6 * 64 + fg8 * 8);
                const uint4 u7 = *(const uint4*)(h_in + s7 * 64 + fg8 * 8);
                accu8(a8, u0);
                if (rem > 1) accu8(a8, u1);
                if (rem > 2) accu8(a8, u2);
                if (rem > 3) accu8(a8, u3);
                if (rem > 4) accu8(a8, u4);
                if (rem > 5) accu8(a8, u5);
                if (rem > 6) accu8(a8, u6);
                if (rem > 7) accu8(a8, u7);
            }
        }

        *(uint4*)&sX1[slot][fg8 * 8] = hreg;
        union { _Float16 h[8]; uint4 u; } cv;
        #pragma unroll
        for (int j = 0; j < 8; ++j) cv.h[j] = (_Float16)a8[j];
        *(uint4*)&sX2[slot][fg8 * 8] = cv.u;
        __syncthreads();

        f32x4 accA1 = {0.f,0.f,0.f,0.f}, accC1 = {0.f,0.f,0.f,0.f};
        f32x4 accB1 = {0.f,0.f,0.f,0.f}, accD1 = {0.f,0.f,0.f,0.f};
        f32x4 accA2 = {0.f,0.f,0.f,0.f}, accC2 = {0.f,0.f,0.f,0.f};
        f32x4 accB2 = {0.f,0.f,0.f,0.f}, accD2 = {0.f,0.f,0.f,0.f};
        #pragma unroll
        for (int kk = 0; kk < 2; ++kk) {
            const int ko = kk * 32 + kh * 8;
            const f16x8 wa = kk ? wrA1 : wrA0;
            const f16x8 wc = kk ? wrC1 : wrC0;
            const f16x8 wb = kk ? wrB1 : wrB0;
            const f16x8 wd = kk ? wrD1 : wrD0;
            const f16x8 a1r0 = *(const f16x8*)&sX1[lr][ko];
            const f16x8 a2r0 = *(const f16x8*)&sX2[lr][ko];
            const f16x8 a1r1 = *(const f16x8*)&sX1[16 + lr][ko];
            const f16x8 a2r1 = *(const f16x8*)&sX2[16 + lr][ko];
            accA1 = __builtin_amdgcn_mfma_f32_16x16x32_f16(a1r0, wa, accA1, 0, 0, 0);
            accC1 = __builtin_amdgcn_mfma_f32_16x16x32_f16(a2r0, wc, accC1, 0, 0, 0);
            accB1 = __builtin_amdgcn_mfma_f32_16x16x32_f16(a1r0, wb, accB1, 0, 0, 0);
            accD1 = __builtin_amdgcn_mfma_f32_16x16x32_f16(a1r0, wd, accD1, 0, 0, 0);
            accA2 = __builtin_amdgcn_mfma_f32_16x16x32_f16(a1r1, wa, accA2, 0, 0, 0);
            accC2 = __builtin_amdgcn_mfma_f32_16x16x32_f16(a2r1, wc, accC2, 0, 0, 0);
            accB2 = __builtin_amdgcn_mfma_f32_16x16x32_f16(a1r1, wb, accB2, 0, 0, 0);
            accD2 = __builtin_amdgcn_mfma_f32_16x16x32_f16(a1r1, wd, accD2, 0, 0, 0);
        }

        #pragma unroll
        for (int r = 0; r < 4; ++r) {
            int nd = node0 + kh * 4 + r;
            if (nd < NN) {
                float o = fmaxf((accA1[r] + bA) + (accC1[r] + bC) +
                                (accB1[r] + bB) * (accD1[r] + bD), 0.f);
                h_out[nd * 64 + col] = __float2half(o);
            }
            nd += 16;
            if (nd < NN) {
                float o = fmaxf((accA2[r] + bA) + (accC2[r] + bC) +
                                (accB2[r] + bB) * (accD2[r] + bD), 0.f);
                h_out[nd * 64 + col] = __float2half(o);
            }
        }
    }
}

// ---------------- pool + MLP (512 threads) ----------------
__global__ __launch_bounds__(512) void pool_mlp_kernel(
    const __half* __restrict__ h, const int* __restrict__ batch,
    const float* __restrict__ w1, const float* __restrict__ b1,
    const float* __restrict__ w2, const float* __restrict__ b2,
    float* __restrict__ out)
{
    const int g = blockIdx.x;
    const int t = threadIdx.x;
    int lo = 0, hi = NN;
    while (lo < hi) { int m = (lo + hi) >> 1; if (batch[m] < g) lo = m + 1; else hi = m; }
    const int start = lo;
    hi = NN;
    while (lo < hi) { int m = (lo + hi) >> 1; if (batch[m] < g + 1) lo = m + 1; else hi = m; }
    const int end = lo;

    const int f = t & 63, wsub = t >> 6;   // wsub 0..7
    float sum = 0.f;
    for (int n = start + wsub; n < end; n += 8) sum += __half2float(h[n * 64 + f]);
    __shared__ float red[8][64];
    red[wsub][f] = sum;
    __syncthreads();
    __shared__ float pooled[64];
    if (t < 64) {
        float tot = 0.f;
        #pragma unroll
        for (int j = 0; j < 8; ++j) tot += red[j][t];
        pooled[t] = tot / fmaxf((float)(end - start), 1.f);
    }
    __syncthreads();
    __shared__ float y10[10];
    if (t < 10) {
        float acc = b1[t];
        for (int k = 0; k < 64; ++k) acc = fmaf(pooled[k], w1[k * 10 + t], acc);
        y10[t] = acc;
    }
    __syncthreads();
    if (t == 0) {
        float acc = b2[0];
        for (int j = 0; j < 10; ++j) acc = fmaf(y10[j], w2[j], acc);
        out[g] = acc;
    }
}

extern "C" void kernel_launch(void* const* d_in, const int* in_sizes, int n_in,
                              void* d_out, int out_size, void* d_ws, size_t ws_size,
                              hipStream_t stream) {
    const float* x   = (const float*)d_in[0];
    const int* ei    = (const int*)d_in[1];
    const int* batch = (const int*)d_in[2];
    const int* src   = ei;
    const int* dstv  = ei + NE;

    // workspace layout (bytes), total ~40MB:
    //   hX16: [0, 12.8M)      hA16: [12.8M, 25.6M)
    //   csr:  [25.6M, 32.0M)  rs: [32.0M, +400004)
    //   binned: [32.5M, +7.23M)  gcur: [39.8M, +1KB)  wt: [39.81M, +98304)
    char* ws     = (char*)d_ws;
    __half* hX16 = (__half*)(ws);
    __half* hA16 = (__half*)(ws + 12800000);
    int* csr     = (int*)(ws + 25600000);
    int* rs      = (int*)(ws + 32000000);
    unsigned int* binned = (unsigned int*)(ws + 32500000);
    int* gcur    = (int*)(ws + 39800000);
    __half* wt   = (__half*)(ws + 39810000);

    auto f = [&](int i) { return (const float*)d_in[i]; };
    W12 wm;
    const int wmidx[12] = {5, 3, 7, 9, 13, 11, 15, 17, 21, 19, 23, 25};
    for (int i = 0; i < 12; ++i) wm.w[i] = f(wmidx[i]);

    hipMemsetAsync(gcur, 0, NBKT * sizeof(int), stream);
    binA_kernel<<<1024, 256, 0, stream>>>(src, dstv, gcur, binned, x, hX16, wm, wt);
    binB_kernel<<<NBKT, 512, 0, stream>>>(binned, gcur, csr, rs);

    layer_kernel<<<LAYER_GRID, 256, 0, stream>>>(hX16, hA16, csr, rs,
        wt,         f(6), f(4), f(8), f(10));
    layer_kernel<<<LAYER_GRID, 256, 0, stream>>>(hA16, hX16, csr, rs,
        wt + 16384, f(14), f(12), f(16), f(18));
    layer_kernel<<<LAYER_GRID, 256, 0, stream>>>(hX16, hA16, csr, rs,
        wt + 32768, f(22), f(20), f(24), f(26));

    pool_mlp_kernel<<<NG, 512, 0, stream>>>(hA16, batch,
        f(27), f(28), f(29), f(30), (float*)d_out);
}

// Round 12
// 200.041 us; speedup vs baseline: 10.8084x; 1.0545x over previous
//
#include <hip/hip_runtime.h>
#include <hip/hip_fp16.h>

#define NN 100000
#define NE 1600000
#define NG 256
#define NPB 32
#define LAYER_GRID 2048                      // 2-pass amortization of per-block prologue (r11: 3136 regressed)
#define SIDX 1280

#define BSH 9
#define NBKT ((NN + 511) / 512)              // 196
#define CAP 9216
#define TILE_A 4096
#define NBLK_A ((NE + TILE_A - 1) / TILE_A)  // 391

typedef _Float16 f16x8 __attribute__((ext_vector_type(8)));
typedef float f32x4 __attribute__((ext_vector_type(4)));

struct W12 { const float* w[12]; };

__device__ __forceinline__ uint2 f4_to_h16(float4 o) {
    __half2 lo = __floats2half2_rn(o.x, o.y);
    __half2 hi = __floats2half2_rn(o.z, o.w);
    uint2 u;
    u.x = *(unsigned int*)&lo;
    u.y = *(unsigned int*)&hi;
    return u;
}

__device__ __forceinline__ void accu8(float* a8, uint4 u) {
    const __half2* hp = (const __half2*)&u;
    #pragma unroll
    for (int q = 0; q < 4; ++q) {
        float2 f = __half22float2(hp[q]);
        a8[2 * q] += f.x; a8[2 * q + 1] += f.y;
    }
}

// ---------------- binA: wprep + cvt prologue, then edge binning ----------------
// gcur holds per-bucket COUNTS (memset to 0 before launch).
__global__ __launch_bounds__(256) void binA_kernel(const int* __restrict__ src,
                                                   const int* __restrict__ dst,
                                                   int* __restrict__ gcur,
                                                   unsigned int* __restrict__ binned,
                                                   const float* __restrict__ x,
                                                   __half* __restrict__ hX16,
                                                   W12 wm, __half* __restrict__ wt)
{
    __shared__ int hist[NBKT];
    __shared__ int cnt2[NBKT];
    __shared__ int lexcl[NBKT];
    __shared__ int base[NBKT];
    __shared__ int s[256];
    __shared__ unsigned int buf[TILE_A];
    __shared__ unsigned char bkt8[TILE_A];

    const int t = threadIdx.x;
    const int gt = blockIdx.x * 256 + t;
    const int gs = gridDim.x * 256;

    // prologue 1: weight prep, 12 mats fp32 [k][n] -> fp16 [n][k]
    for (int i = gt; i < 12 * 4096; i += gs) {
        const int m = i >> 12, e = i & 4095;
        const int n = e >> 6, k = e & 63;
        wt[m * 4096 + n * 64 + k] = __float2half(wm.w[m][k * 64 + n]);
    }
    // prologue 2: cvt x fp32 -> fp16
    for (int i = gt; i < NN * 64 / 4; i += gs) {
        float4 v = ((const float4*)x)[i];
        ((uint2*)hX16)[i] = f4_to_h16(v);
    }

    // edge binning with LDS reorder (contiguous per-bucket runs to global)
    for (int tile = blockIdx.x; tile < NBLK_A; tile += gridDim.x) {
        const int e0 = tile * TILE_A;
        const int nedge = min(TILE_A, NE - e0);
        __syncthreads();
        if (t < NBKT) { hist[t] = 0; cnt2[t] = 0; }
        __syncthreads();

        for (int j = t; j < nedge; j += 256)
            atomicAdd(&hist[dst[e0 + j] >> BSH], 1);
        __syncthreads();

        s[t] = (t < NBKT) ? hist[t] : 0;
        __syncthreads();
        for (int off = 1; off < 256; off <<= 1) {
            int u = (t >= off) ? s[t - off] : 0;
            __syncthreads();
            s[t] += u;
            __syncthreads();
        }
        if (t < NBKT) {
            lexcl[t] = s[t] - hist[t];
            if (hist[t] > 0) base[t] = t * CAP + atomicAdd(&gcur[t], hist[t]);
        }
        __syncthreads();

        for (int j = t; j < nedge; j += 256) {
            const int d = dst[e0 + j];
            const int sv = src[e0 + j];
            const int b = d >> BSH;
            const int r = atomicAdd(&cnt2[b], 1);
            const int idx = lexcl[b] + r;
            buf[idx] = ((unsigned int)sv << BSH) | (unsigned int)(d & 511);
            bkt8[idx] = (unsigned char)b;
        }
        __syncthreads();

        for (int j = t; j < nedge; j += 256) {
            const int b = bkt8[j];
            binned[base[b] + (j - lexcl[b])] = buf[j];
        }
    }
}

// ---------------- binB: local bucket-base scan + per-bucket counting sort ----------------
__global__ __launch_bounds__(512) void binB_kernel(const unsigned int* __restrict__ binned,
                                                   const int* __restrict__ gcur,
                                                   int* __restrict__ csr,
                                                   int* __restrict__ rs)
{
    __shared__ int cnt[512];
    __shared__ int excl[512];
    __shared__ int cnt2[512];
    __shared__ int psum[256];
    __shared__ unsigned int buf[CAP];
    __shared__ int gbs;

    const int b = blockIdx.x;
    const int t = threadIdx.x;

    // local exclusive scan of bucket sizes -> this block's global base (threads <256)
    int szt = 0;
    if (t < 256) {
        szt = (t < NBKT) ? min(gcur[t], CAP) : 0;
        psum[t] = szt;
    }
    __syncthreads();
    for (int off = 1; off < 256; off <<= 1) {
        int u = 0;
        if (t < 256 && t >= off) u = psum[t - off];
        __syncthreads();
        if (t < 256) psum[t] += u;
        __syncthreads();
    }
    if (t == b) gbs = psum[t] - szt;   // b < NBKT=196 < 256
    __syncthreads();
    const int sz = min(gcur[b], CAP);
    const int gb = gbs;
    const unsigned int* bp = binned + b * CAP;

    cnt[t] = 0;
    cnt2[t] = 0;
    __syncthreads();

    for (int j = t; j < sz; j += 512) {
        const unsigned int v = bp[j];
        buf[j] = v;
        atomicAdd(&cnt[v & 511], 1);
    }
    __syncthreads();

    int c0 = 0, c1 = 0;
    if (t < 256) {
        c0 = cnt[2 * t]; c1 = cnt[2 * t + 1];
        psum[t] = c0 + c1;
    }
    __syncthreads();
    for (int off = 1; off < 256; off <<= 1) {
        int u = 0;
        if (t < 256 && t >= off) u = psum[t - off];
        __syncthreads();
        if (t < 256) psum[t] += u;
        __syncthreads();
    }
    if (t < 256) {
        const int pe = psum[t] - (c0 + c1);
        excl[2 * t] = pe;
        excl[2 * t + 1] = pe + c0;
    }
    __syncthreads();

    const int node0 = b << BSH;
    {
        const int node = node0 + t;
        if (t < 512 && node < NN) rs[node] = gb + excl[t];
    }
    for (int j = t; j < sz; j += 512) {
        const unsigned int v = buf[j];
        const int l = v & 511;
        const int r = atomicAdd(&cnt2[l], 1);
        csr[gb + excl[l] + r] = (int)(v >> BSH);
    }
    if (b == 0 && t == 0) rs[NN] = NE;
}

// ---------------- fused GNN layer: MFMA dense + gathered agg ----------------
__global__ __launch_bounds__(256) void layer_kernel(
    const __half* __restrict__ h_in, __half* __restrict__ h_out,
    const int* __restrict__ csr, const int* __restrict__ rs,
    const __half* __restrict__ wt,
    const float* __restrict__ ba, const float* __restrict__ bc,
    const float* __restrict__ bb, const float* __restrict__ bd)
{
    __shared__ _Float16 sX1[NPB][72];
    __shared__ _Float16 sX2[NPB][72];
    __shared__ int sIdx[SIDX];

    const int tid = threadIdx.x;
    const int slot = tid >> 3, fg8 = tid & 7;
    const int w = tid >> 6, l = tid & 63, lr = l & 15, kh = l >> 4;
    const int col = w * 16 + lr;

    const _Float16* wtf = (const _Float16*)wt;
    const f16x8 wrA0 = *(const f16x8*)&wtf[0 * 4096 + col * 64 + kh * 8];
    const f16x8 wrA1 = *(const f16x8*)&wtf[0 * 4096 + col * 64 + 32 + kh * 8];
    const f16x8 wrC0 = *(const f16x8*)&wtf[1 * 4096 + col * 64 + kh * 8];
    const f16x8 wrC1 = *(const f16x8*)&wtf[1 * 4096 + col * 64 + 32 + kh * 8];
    const f16x8 wrB0 = *(const f16x8*)&wtf[2 * 4096 + col * 64 + kh * 8];
    const f16x8 wrB1 = *(const f16x8*)&wtf[2 * 4096 + col * 64 + 32 + kh * 8];
    const f16x8 wrD0 = *(const f16x8*)&wtf[3 * 4096 + col * 64 + kh * 8];
    const f16x8 wrD1 = *(const f16x8*)&wtf[3 * 4096 + col * 64 + 32 + kh * 8];
    const float bA = ba[col], bC = bc[col], bB = bb[col], bD = bd[col];

    const int npass = (NN + NPB - 1) / NPB;
    for (int g = blockIdx.x; g < npass; g += gridDim.x) {
        const int node0 = g * NPB;
        const int e0 = rs[node0];
        const int eN = rs[min(node0 + NPB, NN)];
        const int staged = min(eN - e0, SIDX);

        __syncthreads();
        for (int j = tid; j < staged; j += 256) sIdx[j] = csr[e0 + j];
        __syncthreads();

        const int node = node0 + slot;
        uint4 hreg = make_uint4(0u, 0u, 0u, 0u);
        float a8[8] = {0.f, 0.f, 0.f, 0.f, 0.f, 0.f, 0.f, 0.f};
        if (node < NN) {
            hreg = *(const uint4*)(h_in + node * 64 + fg8 * 8);
            const int rsn = rs[node];
            const int ne = rs[node + 1] - rsn;
            const int le = rsn - e0;
            for (int q = 0; q < ne; q += 8) {
                const int rem = ne - q;
                const int jb = le + q;
                auto gi = [&](int i) {
                    const int jr = jb + i;
                    return (jr < staged) ? sIdx[jr] : csr[e0 + jr];
                };
                const int s0 = gi(0);
                const int s1 = rem > 1 ? gi(1) : s0;
                const int s2 = rem > 2 ? gi(2) : s0;
                const int s3 = rem > 3 ? gi(3) : s0;
                const int s4 = rem > 4 ? gi(4) : s0;
                const int s5 = rem > 5 ? gi(5) : s0;
                const int s6 = rem > 6 ? gi(6) : s0;
                const int s7 = rem > 7 ? gi(7) : s0;
                const uint4 u0 = *(const uint4*)(h_in + s0 * 64 + fg8 * 8);
                const uint4 u1 = *(const uint4*)(h_in + s1 * 64 + fg8 * 8);
                const uint4 u2 = *(const uint4*)(h_in + s2 * 64 + fg8 * 8);
                const uint4 u3 = *(const uint4*)(h_in + s3 * 64 + fg8 * 8);
                const uint4 u4 = *(const uint4*)(h_in + s4 * 64 + fg8 * 8);
                const uint4 u5 = *(const uint4*)(h_in + s5 * 64 + fg8 * 8);
                const uint4 u6 = *(const uint4*)(h_in + s6 * 64 + fg8 * 8);
                const uint4 u7 = *(const uint4*)(h_in + s7 * 64 + fg8 * 8);
                accu8(a8, u0);
                if (rem > 1) accu8(a8, u1);
                if (rem > 2) accu8(a8, u2);
                if (rem > 3) accu8(a8, u3);
                if (rem > 4) accu8(a8, u4);
                if (rem > 5) accu8(a8, u5);
                if (rem > 6) accu8(a8, u6);
                if (rem > 7) accu8(a8, u7);
            }
        }

        *(uint4*)&sX1[slot][fg8 * 8] = hreg;
        union { _Float16 h[8]; uint4 u; } cv;
        #pragma unroll
        for (int j = 0; j < 8; ++j) cv.h[j] = (_Float16)a8[j];
        *(uint4*)&sX2[slot][fg8 * 8] = cv.u;
        __syncthreads();

        f32x4 accA1 = {0.f,0.f,0.f,0.f}, accC1 = {0.f,0.f,0.f,0.f};
        f32x4 accB1 = {0.f,0.f,0.f,0.f}, accD1 = {0.f,0.f,0.f,0.f};
        f32x4 accA2 = {0.f,0.f,0.f,0.f}, accC2 = {0.f,0.f,0.f,0.f};
        f32x4 accB2 = {0.f,0.f,0.f,0.f}, accD2 = {0.f,0.f,0.f,0.f};
        #pragma unroll
        for (int kk = 0; kk < 2; ++kk) {
            const int ko = kk * 32 + kh * 8;
            const f16x8 wa = kk ? wrA1 : wrA0;
            const f16x8 wc = kk ? wrC1 : wrC0;
            const f16x8 wb = kk ? wrB1 : wrB0;
            const f16x8 wd = kk ? wrD1 : wrD0;
            const f16x8 a1r0 = *(const f16x8*)&sX1[lr][ko];
            const f16x8 a2r0 = *(const f16x8*)&sX2[lr][ko];
            const f16x8 a1r1 = *(const f16x8*)&sX1[16 + lr][ko];
            const f16x8 a2r1 = *(const f16x8*)&sX2[16 + lr][ko];
            accA1 = __builtin_amdgcn_mfma_f32_16x16x32_f16(a1r0, wa, accA1, 0, 0, 0);
            accC1 = __builtin_amdgcn_mfma_f32_16x16x32_f16(a2r0, wc, accC1, 0, 0, 0);
            accB1 = __builtin_amdgcn_mfma_f32_16x16x32_f16(a1r0, wb, accB1, 0, 0, 0);
            accD1 = __builtin_amdgcn_mfma_f32_16x16x32_f16(a1r0, wd, accD1, 0, 0, 0);
            accA2 = __builtin_amdgcn_mfma_f32_16x16x32_f16(a1r1, wa, accA2, 0, 0, 0);
            accC2 = __builtin_amdgcn_mfma_f32_16x16x32_f16(a2r1, wc, accC2, 0, 0, 0);
            accB2 = __builtin_amdgcn_mfma_f32_16x16x32_f16(a1r1, wb, accB2, 0, 0, 0);
            accD2 = __builtin_amdgcn_mfma_f32_16x16x32_f16(a1r1, wd, accD2, 0, 0, 0);
        }

        #pragma unroll
        for (int r = 0; r < 4; ++r) {
            int nd = node0 + kh * 4 + r;
            if (nd < NN) {
                float o = fmaxf((accA1[r] + bA) + (accC1[r] + bC) +
                                (accB1[r] + bB) * (accD1[r] + bD), 0.f);
                h_out[nd * 64 + col] = __float2half(o);
            }
            nd += 16;
            if (nd < NN) {
                float o = fmaxf((accA2[r] + bA) + (accC2[r] + bC) +
                                (accB2[r] + bB) * (accD2[r] + bD), 0.f);
                h_out[nd * 64 + col] = __float2half(o);
            }
        }
    }
}

// ---------------- pool + MLP (512 threads) ----------------
__global__ __launch_bounds__(512) void pool_mlp_kernel(
    const __half* __restrict__ h, const int* __restrict__ batch,
    const float* __restrict__ w1, const float* __restrict__ b1,
    const float* __restrict__ w2, const float* __restrict__ b2,
    float* __restrict__ out)
{
    const int g = blockIdx.x;
    const int t = threadIdx.x;
    int lo = 0, hi = NN;
    while (lo < hi) { int m = (lo + hi) >> 1; if (batch[m] < g) lo = m + 1; else hi = m; }
    const int start = lo;
    hi = NN;
    while (lo < hi) { int m = (lo + hi) >> 1; if (batch[m] < g + 1) lo = m + 1; else hi = m; }
    const int end = lo;

    const int f = t & 63, wsub = t >> 6;   // wsub 0..7
    float sum = 0.f;
    for (int n = start + wsub; n < end; n += 8) sum += __half2float(h[n * 64 + f]);
    __shared__ float red[8][64];
    red[wsub][f] = sum;
    __syncthreads();
    __shared__ float pooled[64];
    if (t < 64) {
        float tot = 0.f;
        #pragma unroll
        for (int j = 0; j < 8; ++j) tot += red[j][t];
        pooled[t] = tot / fmaxf((float)(end - start), 1.f);
    }
    __syncthreads();
    __shared__ float y10[10];
    if (t < 10) {
        float acc = b1[t];
        for (int k = 0; k < 64; ++k) acc = fmaf(pooled[k], w1[k * 10 + t], acc);
        y10[t] = acc;
    }
    __syncthreads();
    if (t == 0) {
        float acc = b2[0];
        for (int j = 0; j < 10; ++j) acc = fmaf(y10[j], w2[j], acc);
        out[g] = acc;
    }
}

extern "C" void kernel_launch(void* const* d_in, const int* in_sizes, int n_in,
                              void* d_out, int out_size, void* d_ws, size_t ws_size,
                              hipStream_t stream) {
    const float* x   = (const float*)d_in[0];
    const int* ei    = (const int*)d_in[1];
    const int* batch = (const int*)d_in[2];
    const int* src   = ei;
    const int* dstv  = ei + NE;

    // workspace layout (bytes), total ~40MB:
    //   hX16: [0, 12.8M)      hA16: [12.8M, 25.6M)
    //   csr:  [25.6M, 32.0M)  rs: [32.0M, +400004)
    //   binned: [32.5M, +7.23M)  gcur: [39.8M, +1KB)  wt: [39.81M, +98304)
    char* ws     = (char*)d_ws;
    __half* hX16 = (__half*)(ws);
    __half* hA16 = (__half*)(ws + 12800000);
    int* csr     = (int*)(ws + 25600000);
    int* rs      = (int*)(ws + 32000000);
    unsigned int* binned = (unsigned int*)(ws + 32500000);
    int* gcur    = (int*)(ws + 39800000);
    __half* wt   = (__half*)(ws + 39810000);

    auto f = [&](int i) { return (const float*)d_in[i]; };
    W12 wm;
    const int wmidx[12] = {5, 3, 7, 9, 13, 11, 15, 17, 21, 19, 23, 25};
    for (int i = 0; i < 12; ++i) wm.w[i] = f(wmidx[i]);

    hipMemsetAsync(gcur, 0, NBKT * sizeof(int), stream);
    binA_kernel<<<1024, 256, 0, stream>>>(src, dstv, gcur, binned, x, hX16, wm, wt);
    binB_kernel<<<NBKT, 512, 0, stream>>>(binned, gcur, csr, rs);

    layer_kernel<<<LAYER_GRID, 256, 0, stream>>>(hX16, hA16, csr, rs,
        wt,         f(6), f(4), f(8), f(10));
    layer_kernel<<<LAYER_GRID, 256, 0, stream>>>(hA16, hX16, csr, rs,
        wt + 16384, f(14), f(12), f(16), f(18));
    layer_kernel<<<LAYER_GRID, 256, 0, stream>>>(hX16, hA16, csr, rs,
        wt + 32768, f(22), f(20), f(24), f(26));

    pool_mlp_kernel<<<NG, 512, 0, stream>>>(hA16, batch,
        f(27), f(28), f(29), f(30), (float*)d_out);
}